// Round 6
// baseline (16851.408 us; speedup 1.0000x reference)
//
#include <hip/hip_runtime.h>

// ---------------- constants ----------------
static constexpr int BB = 32, TI = 2000, TT = 1000, CIN = 80, F = 256, KW = 11;
static constexpr int G4 = 2048, V = 29;
static constexpr int MROWS = TT * BB;   // 32000
static constexpr int KC = 896;          // conv K (11*80=880) padded to mult of 64
static constexpr int CH = 100;          // steps per recurrence chunk
static constexpr int NCH = TT / CH;     // 10 chunks
static constexpr int CROWS = CH * BB;   // 3200 rows per chunk
static constexpr int NFLG = 128 * 2 * 16 * 32;  // mailbox ring: (s&127, d, consumer, producer-word)

using short8 = __attribute__((ext_vector_type(8))) short;
using f32x4  = __attribute__((ext_vector_type(4))) float;

#define DEV __device__ __forceinline__

DEV ushort f2bf(float f) {
  unsigned u = __float_as_uint(f);
  unsigned r = (u + 0x7FFFu + ((u >> 16) & 1u)) >> 16;
  return (ushort)r;
}
DEV float bf2f(ushort h) { return __uint_as_float(((unsigned)h) << 16); }
DEV float sigm(float x) { return 1.f / (1.f + __expf(-x)); }
DEV float tanhft(float x) { return 1.f - 2.f / (__expf(2.f * x) + 1.f); }

// ---------------- prep kernels ----------------
__global__ void k_zero(int* p, int n) {
  int i = blockIdx.x * blockDim.x + threadIdx.x;
  if (i < n) p[i] = 0;
}

// conv_w [11][80][256] -> CW [256][896] bf16 (K padded w/ zeros)
__global__ void k_convw(const float* __restrict__ w, ushort* __restrict__ dst) {
  int idx = blockIdx.x * blockDim.x + threadIdx.x;
  if (idx >= F * KC) return;
  int f = idx / KC, kk = idx % KC;
  float v = (kk < KW * CIN) ? w[(size_t)kk * F + f] : 0.f;
  dst[idx] = f2bf(v);
}

// src [K][N] fp32 -> dst [N][K] bf16
__global__ void k_transp(const float* __restrict__ src, ushort* __restrict__ dst, int K, int N) {
  int idx = blockIdx.x * blockDim.x + threadIdx.x;
  if (idx >= K * N) return;
  int n = idx / K, k = idx % K;
  dst[idx] = f2bf(src[(size_t)k * N + n]);
}

// wh [512][2048] fp32 (f and b) -> packed MFMA B-fragments for the rec kernel.
// linear idx = ((((d*16+part)*8+w)*16+kk)*64+lane)*8 + j
__global__ void k_whr(const float* __restrict__ whf, const float* __restrict__ whb,
                      ushort* __restrict__ dst) {
  int idx = blockIdx.x * blockDim.x + threadIdx.x;
  if (idx >= (1 << 21)) return;
  int j = idx & 7, lane = (idx >> 3) & 63, kk = (idx >> 9) & 15;
  int w = (idx >> 13) & 7, part = (idx >> 16) & 15, d = (idx >> 20) & 1;
  int c16 = lane & 15, q = lane >> 4;
  int jj = w * 4 + (c16 >> 2), g = c16 & 3;
  int k = kk * 32 + q * 8 + j;
  int col = g * 512 + part * 32 + jj;
  const float* s = d ? whb : whf;
  dst[idx] = f2bf(s[(size_t)k * G4 + col]);
}

// x [32][2000][80] fp32 -> A0 [3200][896] bf16 im2col chunk (rows: (pos-pos0)*32+b)
__global__ void k_im2col(const float* __restrict__ x, ushort* __restrict__ A0, int pos0) {
  int idx = blockIdx.x * blockDim.x + threadIdx.x;
  if (idx >= CROWS * KC) return;
  int row = idx / KC, kk = idx % KC;
  int pos = pos0 + (row >> 5), b = row & 31;
  float v = 0.f;
  if (kk < KW * CIN) {
    int k = kk / CIN, c = kk % CIN;
    int tx = 2 * pos + k - 4;
    if (tx >= 0 && tx < TI) v = x[((size_t)b * TI + tx) * CIN + c];
  }
  A0[idx] = f2bf(v);
}

// ---------------- GEMM: C = A[.,K] * BT[N,K]^T + bias (bf16 in/out, fp32 acc) ----------
// grid (Mtiles, N/128). 128x128 tile, BK=64, 4 waves, 4x4 16x16 frags/wave.
// tmode=0: C[row*N+col] (optional relu). tmode=1: C[col*CROWS+row] packed 4-row stores.
__global__ __launch_bounds__(256, 2) void k_gemm(const ushort* __restrict__ A,
                                                 const ushort* __restrict__ BT,
                                                 const float* __restrict__ bias,
                                                 ushort* __restrict__ C,
                                                 int N, int K, int relu, int tmode) {
  __shared__ ushort As[128 * 64];
  __shared__ ushort Bs[128 * 64];
  const int tid = threadIdx.x;
  const int lane = tid & 63, wid = tid >> 6;
  const int wm = wid >> 1, wn = wid & 1;
  const int l16 = lane & 15, q = lane >> 4;
  const int bm = blockIdx.x, bn = blockIdx.y;
  const int srow = tid >> 1, scol = (tid & 1) * 32;
  const ushort* ga = A + (size_t)(bm * 128 + srow) * K + scol;
  const ushort* gb = BT + (size_t)(bn * 128 + srow) * K + scol;

  f32x4 acc[4][4] = {};
  uint4 va[4], vb[4];
#pragma unroll
  for (int i = 0; i < 4; i++) { va[i] = ((const uint4*)ga)[i]; vb[i] = ((const uint4*)gb)[i]; }

  for (int k0 = 0; k0 < K; k0 += 64) {
    __syncthreads();
#pragma unroll
    for (int i = 0; i < 4; i++) {
      *(uint4*)&As[srow * 64 + scol + i * 8] = va[i];
      *(uint4*)&Bs[srow * 64 + scol + i * 8] = vb[i];
    }
    __syncthreads();
    if (k0 + 64 < K) {
      const ushort* na = ga + k0 + 64;
      const ushort* nb = gb + k0 + 64;
#pragma unroll
      for (int i = 0; i < 4; i++) { va[i] = ((const uint4*)na)[i]; vb[i] = ((const uint4*)nb)[i]; }
    }
#pragma unroll
    for (int kk = 0; kk < 2; kk++) {
      short8 af[4], bf[4];
#pragma unroll
      for (int mt = 0; mt < 4; mt++)
        af[mt] = *(const short8*)&As[(wm * 64 + mt * 16 + l16) * 64 + kk * 32 + q * 8];
#pragma unroll
      for (int nt = 0; nt < 4; nt++)
        bf[nt] = *(const short8*)&Bs[(wn * 64 + nt * 16 + l16) * 64 + kk * 32 + q * 8];
#pragma unroll
      for (int mt = 0; mt < 4; mt++)
#pragma unroll
        for (int nt = 0; nt < 4; nt++)
          acc[mt][nt] = __builtin_amdgcn_mfma_f32_16x16x32_bf16(af[mt], bf[nt], acc[mt][nt], 0, 0, 0);
    }
  }
  if (tmode == 0) {
#pragma unroll
    for (int mt = 0; mt < 4; mt++) {
#pragma unroll
      for (int nt = 0; nt < 4; nt++) {
        int col = bn * 128 + wn * 64 + nt * 16 + l16;
        float bv = bias[col];
#pragma unroll
        for (int r = 0; r < 4; r++) {
          int row = bm * 128 + wm * 64 + mt * 16 + q * 4 + r;
          float v = acc[mt][nt][r] + bv;
          if (relu) v = fmaxf(v, 0.f);
          C[(size_t)row * N + col] = f2bf(v);
        }
      }
    }
  } else {
#pragma unroll
    for (int mt = 0; mt < 4; mt++) {
#pragma unroll
      for (int nt = 0; nt < 4; nt++) {
        int col = bn * 128 + wn * 64 + nt * 16 + l16;
        float bv = bias[col];
        ushort4 pk;
        pk.x = f2bf(acc[mt][nt][0] + bv);
        pk.y = f2bf(acc[mt][nt][1] + bv);
        pk.z = f2bf(acc[mt][nt][2] + bv);
        pk.w = f2bf(acc[mt][nt][3] + bv);
        int row = bm * 128 + wm * 64 + mt * 16 + q * 4;
        *(ushort4*)&C[(size_t)col * CROWS + row] = pk;
      }
    }
  }
}

// ---------------- persistent BiLSTM recurrence chunk (one layer, both directions) ----------
// 32 blocks x 512 threads; processes global steps [s0, s0+CH).
// block = (d<<4)|part: d=dir, part owns h-cols [part*32, part*32+32).
// Sync: per-consumer mailbox flags (one 128B line per (step,dir,consumer)) + per-wave gather.
// Producer at step s broadcasts tag=tagbase+s into all 16 consumer lines; consumer wave w
// polls only producers 2w,2w+1 in ITS OWN line -> exactly one poller per cacheline.
__global__ __launch_bounds__(512, 1) void k_rec(const ushort* __restrict__ xgf,
                                                const ushort* __restrict__ xgb,
                                                const ushort* __restrict__ whr,
                                                ushort* __restrict__ hout,
                                                int* __restrict__ flags,
                                                float* __restrict__ cstbuf,
                                                int s0, int tagbase) {
  __shared__ ushort hs[32 * 512];  // 32KB, rows XOR-swizzled by ((row&7)<<4) bytes
  const int tid = threadIdx.x, lane = tid & 63, w = tid >> 6;
  const int part = blockIdx.x & 15, d = blockIdx.x >> 4;
  const int l16 = lane & 15, q = lane >> 4;
  const ushort* xg = d ? xgb : xgf;   // transposed layout [2048][CROWS]
  float* cs = cstbuf + ((size_t)blockIdx.x * 512 + tid) * 8;

  short8 wf[16];
  {
    const ushort* p = whr + (((size_t)(d * 16 + part) * 8 + w) * 16 * 64 + lane) * 8;
#pragma unroll
    for (int kk = 0; kk < 16; kk++) wf[kk] = *(const short8*)(p + (size_t)kk * 64 * 8);
  }
  const int jj = w * 4 + (l16 >> 2), g = l16 & 3;
  const int gcol = g * 512 + part * 32 + jj;   // column in xg [2048], gate order i,f,g,o
  const int hcol = part * 32 + jj;             // column in h [512]
  float cst[2][4];
#pragma unroll
  for (int mt = 0; mt < 2; mt++)
#pragma unroll
    for (int r = 0; r < 4; r++) cst[mt][r] = (s0 == 0) ? 0.f : cs[mt * 4 + r];

  for (int ls = 0; ls < CH; ls++) {
    const int s = s0 + ls;
    const int pos = d ? (999 - s) : s;
    const int lp = d ? (CH - 1 - ls) : ls;    // local row block in xg chunk buffer
    // prefetch xt from transposed xg: 2x8B contiguous per thread (overlaps poll latency)
    const ushort* xc = xg + (size_t)gcol * CROWS + lp * 32 + q * 4;
    ushort4 xt0 = *(const ushort4*)(xc);        // rows q*4 + 0..3   (mt=0)
    ushort4 xt1 = *(const ushort4*)(xc + 16);   // rows 16+q*4+0..3  (mt=1)

    if (s == 0) {
      uint4 z4 = {0, 0, 0, 0};
#pragma unroll
      for (int i = 0; i < 4; i++) ((uint4*)hs)[tid * 4 + i] = z4;
    } else {
      const int prod = 2 * w + (lane >> 5);   // producer part gathered by this half-wave
      const int row = lane & 31;              // batch row
      if (ls > 0) {  // first step of a chunk: prev step finished in prior dispatch
        const int sm1 = s - 1;
        const int* fb = flags + ((((size_t)(sm1 & 127) * 2 + d) * 16 + part) * 32) + 2 * w;
        const int tgt = tagbase + sm1;
        int vv;
        do {
          vv = __hip_atomic_load(fb + (lane & 1), __ATOMIC_RELAXED, __HIP_MEMORY_SCOPE_AGENT);
        } while (!__all(vv == tgt));
        asm volatile("" ::: "memory");
      }
      const int ppos = d ? pos + 1 : pos - 1;
      const unsigned long long* gbase =
          (const unsigned long long*)(hout + ((size_t)ppos * 32 + row) * 1024 + d * 512 + prod * 32);
      unsigned long long hv8[8];
#pragma unroll
      for (int k = 0; k < 8; k++)
        hv8[k] = __hip_atomic_load(gbase + k, __ATOMIC_RELAXED, __HIP_MEMORY_SCOPE_AGENT);
      const int swz = (row & 7) << 4;
      char* L = (char*)hs + row * 1024;
      const int cb = prod * 64;
#pragma unroll
      for (int k = 0; k < 8; k++)
        *(unsigned long long*)(L + ((cb + k * 8) ^ swz)) = hv8[k];
    }
    __syncthreads();

    f32x4 za[2] = {};
#pragma unroll
    for (int kk = 0; kk < 16; kk++) {
#pragma unroll
      for (int mt = 0; mt < 2; mt++) {
        int row = mt * 16 + l16;
        int cb = kk * 64 + q * 16;
        short8 a = *(const short8*)((char*)hs + row * 1024 + (cb ^ ((row & 7) << 4)));
        za[mt] = __builtin_amdgcn_mfma_f32_16x16x32_bf16(a, wf[kk], za[mt], 0, 0, 0);
      }
    }

#pragma unroll
    for (int mt = 0; mt < 2; mt++) {
#pragma unroll
      for (int r = 0; r < 4; r++) {
        int bt = mt * 16 + q * 4 + r;
        ushort xr = (mt == 0) ? ((r == 0) ? xt0.x : (r == 1) ? xt0.y : (r == 2) ? xt0.z : xt0.w)
                              : ((r == 0) ? xt1.x : (r == 1) ? xt1.y : (r == 2) ? xt1.z : xt1.w);
        float z = za[mt][r] + bf2f(xr);
        int base = lane & ~3;
        float zi = __shfl(z, base + 0);
        float zf = __shfl(z, base + 1);
        float zg = __shfl(z, base + 2);
        float zo = __shfl(z, base + 3);
        float cn = sigm(zf) * cst[mt][r] + sigm(zi) * tanhft(zg);
        cst[mt][r] = cn;
        float hv = sigm(zo) * tanhft(cn);
        if (g == 0)
          __hip_atomic_store(hout + ((size_t)pos * 32 + bt) * 1024 + d * 512 + hcol, f2bf(hv),
                             __ATOMIC_RELAXED, __HIP_MEMORY_SCOPE_AGENT);
      }
    }
    __syncthreads();  // vmcnt(0) per wave at barrier: all h stores complete before tags go out
    if (tid < 16) {   // broadcast tag into each consumer's private mailbox line
      int* fp = flags + ((((size_t)(s & 127) * 2 + d) * 16 + tid) * 32) + part;
      __hip_atomic_store(fp, tagbase + s, __ATOMIC_RELAXED, __HIP_MEMORY_SCOPE_AGENT);
    }
  }
#pragma unroll
  for (int mt = 0; mt < 2; mt++)
#pragma unroll
    for (int r = 0; r < 4; r++) cs[mt * 4 + r] = cst[mt][r];
}

// ---------------- dense: out[b][pos][29] = h2[row,1024] . W[1024,29] + bias ------------
__global__ __launch_bounds__(256, 2) void k_dense(const ushort* __restrict__ h2,
                                                  const float* __restrict__ wd,
                                                  const float* __restrict__ bd,
                                                  float* __restrict__ out) {
  __shared__ ushort rs[8 * 1024];
  const int tid = threadIdx.x;
  const int r0 = blockIdx.x * 8;
  const uint4* src = (const uint4*)(h2 + (size_t)r0 * 1024);
#pragma unroll
  for (int i = 0; i < 4; i++) ((uint4*)rs)[tid * 4 + i] = src[tid * 4 + i];
  __syncthreads();
  if (tid < 8 * V) {
    const int rr = tid / V, v = tid % V;
    float acc = bd[v];
    const ushort* rp = rs + rr * 1024;
#pragma unroll 8
    for (int k = 0; k < 1024; k++) acc += bf2f(rp[k]) * wd[(size_t)k * V + v];
    const int row = r0 + rr, pos = row >> 5, b = row & 31;
    out[((size_t)b * TT + pos) * V + v] = acc;
  }
}

// ---------------- host ----------------
extern "C" void kernel_launch(void* const* d_in, const int* in_sizes, int n_in,
                              void* d_out, int out_size, void* d_ws, size_t ws_size,
                              hipStream_t stream) {
  const float* x      = (const float*)d_in[0];
  const float* conv_w = (const float*)d_in[1];
  const float* conv_b = (const float*)d_in[2];
  const float* wi1f = (const float*)d_in[3];
  const float* wh1f = (const float*)d_in[4];
  const float* b1f  = (const float*)d_in[5];
  const float* wi1b = (const float*)d_in[6];
  const float* wh1b = (const float*)d_in[7];
  const float* b1b  = (const float*)d_in[8];
  const float* wi2f = (const float*)d_in[9];
  const float* wh2f = (const float*)d_in[10];
  const float* b2f  = (const float*)d_in[11];
  const float* wi2b = (const float*)d_in[12];
  const float* wh2b = (const float*)d_in[13];
  const float* b2b  = (const float*)d_in[14];
  const float* wd   = (const float*)d_in[15];
  const float* bd   = (const float*)d_in[16];
  float* out = (float*)d_out;

  char* ws = (char*)d_ws;
  size_t o = 0;
  auto alloc = [&](size_t sz) { size_t r = o; o = (o + sz + 255) & ~(size_t)255; return r; };
  const size_t oH2  = alloc((size_t)MROWS * 1024 * 2);  // 65.5MB; Y overlays first 16.4MB
  const size_t oY   = oH2;                              // conv out, dead before rec2 writes H2
  const size_t oXGF = alloc((size_t)CROWS * G4 * 2);    // 13.1MB chunk buffer (also im2col scratch)
  const size_t oXGB = alloc((size_t)CROWS * G4 * 2);
  const size_t oH1  = alloc((size_t)MROWS * 1024 * 2);
  const size_t oCW  = alloc((size_t)F * KC * 2);
  const size_t oW1F = alloc((size_t)G4 * F * 2);
  const size_t oW1B = alloc((size_t)G4 * F * 2);
  const size_t oW2F = alloc((size_t)G4 * 1024 * 2);
  const size_t oW2B = alloc((size_t)G4 * 1024 * 2);
  const size_t oR1  = alloc((size_t)(1 << 21) * 2);
  const size_t oR2  = alloc((size_t)(1 << 21) * 2);
  const size_t oCST = alloc((size_t)32 * 512 * 8 * 4);
  const size_t oFL  = alloc((size_t)NFLG * 4);          // 512KB mailbox ring
  if (ws_size < o) return;  // workspace insufficient (~177MB needed)

  ushort* H2  = (ushort*)(ws + oH2);
  ushort* Y   = (ushort*)(ws + oY);
  ushort* XGF = (ushort*)(ws + oXGF);
  ushort* XGB = (ushort*)(ws + oXGB);
  ushort* H1  = (ushort*)(ws + oH1);
  ushort* CW  = (ushort*)(ws + oCW);
  ushort* W1F = (ushort*)(ws + oW1F);
  ushort* W1B = (ushort*)(ws + oW1B);
  ushort* W2F = (ushort*)(ws + oW2F);
  ushort* W2B = (ushort*)(ws + oW2B);
  ushort* R1  = (ushort*)(ws + oR1);
  ushort* R2  = (ushort*)(ws + oR2);
  float*  CST = (float*)(ws + oCST);
  int*    FL  = (int*)(ws + oFL);

  hipLaunchKernelGGL(k_zero, dim3((NFLG + 255) / 256), dim3(256), 0, stream, FL, NFLG);
  hipLaunchKernelGGL(k_convw, dim3((F * KC + 255) / 256), dim3(256), 0, stream, conv_w, CW);
  hipLaunchKernelGGL(k_transp, dim3((F * G4 + 255) / 256), dim3(256), 0, stream, wi1f, W1F, F, G4);
  hipLaunchKernelGGL(k_transp, dim3((F * G4 + 255) / 256), dim3(256), 0, stream, wi1b, W1B, F, G4);
  hipLaunchKernelGGL(k_transp, dim3((1024 * G4 + 255) / 256), dim3(256), 0, stream, wi2f, W2F, 1024, G4);
  hipLaunchKernelGGL(k_transp, dim3((1024 * G4 + 255) / 256), dim3(256), 0, stream, wi2b, W2B, 1024, G4);
  hipLaunchKernelGGL(k_whr, dim3((1 << 21) / 256), dim3(256), 0, stream, wh1f, wh1b, R1);
  hipLaunchKernelGGL(k_whr, dim3((1 << 21) / 256), dim3(256), 0, stream, wh2f, wh2b, R2);

  // conv as chunked im2col + GEMM (+bias+relu) -> Y bf16 [32000,256] (row-major)
  for (int p = 0; p < NCH; ++p) {
    hipLaunchKernelGGL(k_im2col, dim3((CROWS * KC + 255) / 256), dim3(256), 0, stream,
                       x, XGF, p * CH);
    hipLaunchKernelGGL(k_gemm, dim3(CROWS / 128, F / 128), dim3(256), 0, stream,
                       XGF, CW, conv_b, Y + (size_t)p * CROWS * F, F, KC, 1, 0);
  }
  // layer 1: chunked projections (transposed xg) + recurrence -> H1 [1000][32][1024]
  for (int p = 0; p < NCH; ++p) {
    hipLaunchKernelGGL(k_gemm, dim3(CROWS / 128, G4 / 128), dim3(256), 0, stream,
                       Y + (size_t)p * CROWS * F, W1F, b1f, XGF, G4, F, 0, 1);
    hipLaunchKernelGGL(k_gemm, dim3(CROWS / 128, G4 / 128), dim3(256), 0, stream,
                       Y + (size_t)(NCH - 1 - p) * CROWS * F, W1B, b1b, XGB, G4, F, 0, 1);
    hipLaunchKernelGGL(k_rec, dim3(32), dim3(512), 0, stream, XGF, XGB, R1, H1, FL, CST,
                       p * CH, 1);
  }
  // layer 2: chunked projections + recurrence -> H2 (tagbase 1001 -> no mailbox collision)
  for (int p = 0; p < NCH; ++p) {
    hipLaunchKernelGGL(k_gemm, dim3(CROWS / 128, G4 / 128), dim3(256), 0, stream,
                       H1 + (size_t)p * CROWS * 1024, W2F, b2f, XGF, G4, 1024, 0, 1);
    hipLaunchKernelGGL(k_gemm, dim3(CROWS / 128, G4 / 128), dim3(256), 0, stream,
                       H1 + (size_t)(NCH - 1 - p) * CROWS * 1024, W2B, b2b, XGB, G4, 1024, 0, 1);
    hipLaunchKernelGGL(k_rec, dim3(32), dim3(512), 0, stream, XGF, XGB, R2, H2, FL, CST,
                       p * CH, 1001);
  }
  // dense
  hipLaunchKernelGGL(k_dense, dim3(MROWS / 8), dim3(256), 0, stream, H2, wd, bd, out);
}

// Round 7
// 16732.315 us; speedup vs baseline: 1.0071x; 1.0071x over previous
//
#include <hip/hip_runtime.h>

// ---------------- constants ----------------
static constexpr int BB = 32, TI = 2000, TT = 1000, CIN = 80, F = 256, KW = 11;
static constexpr int G4 = 2048, V = 29;
static constexpr int MROWS = TT * BB;   // 32000
static constexpr int KC = 896;          // conv K (11*80=880) padded to mult of 64
static constexpr int CH = 100;          // steps per recurrence chunk
static constexpr int NCH = TT / CH;     // 10 chunks
static constexpr int CROWS = CH * BB;   // 3200 rows per chunk
static constexpr unsigned SENT = 0x7FC0u;            // bf16 NaN: h can never produce it
static constexpr unsigned SENT2 = 0x7FC07FC0u;

using short8 = __attribute__((ext_vector_type(8))) short;
using f32x4  = __attribute__((ext_vector_type(4))) float;

#define DEV __device__ __forceinline__

DEV ushort f2bf(float f) {
  unsigned u = __float_as_uint(f);
  unsigned r = (u + 0x7FFFu + ((u >> 16) & 1u)) >> 16;
  return (ushort)r;
}
DEV float bf2f(ushort h) { return __uint_as_float(((unsigned)h) << 16); }
DEV float sigm(float x) { return 1.f / (1.f + __expf(-x)); }
DEV float tanhft(float x) { return 1.f - 2.f / (__expf(2.f * x) + 1.f); }

// word accepted iff no 16-bit half equals the sentinel
DEV bool ok4(unsigned long long v) {
  unsigned lo = (unsigned)v, hi = (unsigned)(v >> 32);
  return ((lo & 0xFFFFu) != SENT) & ((lo >> 16) != SENT) &
         ((hi & 0xFFFFu) != SENT) & ((hi >> 16) != SENT);
}

// ---------------- prep kernels ----------------
// fill n8 * 8 ushorts with sentinel (uint4 = 8 bf16 per thread)
__global__ void k_fillsent(uint4* p, int n8) {
  int i = blockIdx.x * blockDim.x + threadIdx.x;
  if (i < n8) { uint4 s = {SENT2, SENT2, SENT2, SENT2}; p[i] = s; }
}

// conv_w [11][80][256] -> CW [256][896] bf16 (K padded w/ zeros)
__global__ void k_convw(const float* __restrict__ w, ushort* __restrict__ dst) {
  int idx = blockIdx.x * blockDim.x + threadIdx.x;
  if (idx >= F * KC) return;
  int f = idx / KC, kk = idx % KC;
  float v = (kk < KW * CIN) ? w[(size_t)kk * F + f] : 0.f;
  dst[idx] = f2bf(v);
}

// src [K][N] fp32 -> dst [N][K] bf16
__global__ void k_transp(const float* __restrict__ src, ushort* __restrict__ dst, int K, int N) {
  int idx = blockIdx.x * blockDim.x + threadIdx.x;
  if (idx >= K * N) return;
  int n = idx / K, k = idx % K;
  dst[idx] = f2bf(src[(size_t)k * N + n]);
}

// wh [512][2048] fp32 (f and b) -> packed MFMA B-fragments for the rec kernel.
// linear idx = ((((d*16+part)*8+w)*16+kk)*64+lane)*8 + j
__global__ void k_whr(const float* __restrict__ whf, const float* __restrict__ whb,
                      ushort* __restrict__ dst) {
  int idx = blockIdx.x * blockDim.x + threadIdx.x;
  if (idx >= (1 << 21)) return;
  int j = idx & 7, lane = (idx >> 3) & 63, kk = (idx >> 9) & 15;
  int w = (idx >> 13) & 7, part = (idx >> 16) & 15, d = (idx >> 20) & 1;
  int c16 = lane & 15, q = lane >> 4;
  int jj = w * 4 + (c16 >> 2), g = c16 & 3;
  int k = kk * 32 + q * 8 + j;
  int col = g * 512 + part * 32 + jj;
  const float* s = d ? whb : whf;
  dst[idx] = f2bf(s[(size_t)k * G4 + col]);
}

// x [32][2000][80] fp32 -> A0 [3200][896] bf16 im2col chunk (rows: (pos-pos0)*32+b)
__global__ void k_im2col(const float* __restrict__ x, ushort* __restrict__ A0, int pos0) {
  int idx = blockIdx.x * blockDim.x + threadIdx.x;
  if (idx >= CROWS * KC) return;
  int row = idx / KC, kk = idx % KC;
  int pos = pos0 + (row >> 5), b = row & 31;
  float v = 0.f;
  if (kk < KW * CIN) {
    int k = kk / CIN, c = kk % CIN;
    int tx = 2 * pos + k - 4;
    if (tx >= 0 && tx < TI) v = x[((size_t)b * TI + tx) * CIN + c];
  }
  A0[idx] = f2bf(v);
}

// ---------------- GEMM: C = A[.,K] * BT[N,K]^T + bias (bf16 in/out, fp32 acc) ----------
// grid (Mtiles, N/128). 128x128 tile, BK=64, 4 waves, 4x4 16x16 frags/wave.
// tmode=0: C[row*N+col] (optional relu). tmode=1: C[col*CROWS+row] packed 4-row stores.
__global__ __launch_bounds__(256, 2) void k_gemm(const ushort* __restrict__ A,
                                                 const ushort* __restrict__ BT,
                                                 const float* __restrict__ bias,
                                                 ushort* __restrict__ C,
                                                 int N, int K, int relu, int tmode) {
  __shared__ ushort As[128 * 64];
  __shared__ ushort Bs[128 * 64];
  const int tid = threadIdx.x;
  const int lane = tid & 63, wid = tid >> 6;
  const int wm = wid >> 1, wn = wid & 1;
  const int l16 = lane & 15, q = lane >> 4;
  const int bm = blockIdx.x, bn = blockIdx.y;
  const int srow = tid >> 1, scol = (tid & 1) * 32;
  const ushort* ga = A + (size_t)(bm * 128 + srow) * K + scol;
  const ushort* gb = BT + (size_t)(bn * 128 + srow) * K + scol;

  f32x4 acc[4][4] = {};
  uint4 va[4], vb[4];
#pragma unroll
  for (int i = 0; i < 4; i++) { va[i] = ((const uint4*)ga)[i]; vb[i] = ((const uint4*)gb)[i]; }

  for (int k0 = 0; k0 < K; k0 += 64) {
    __syncthreads();
#pragma unroll
    for (int i = 0; i < 4; i++) {
      *(uint4*)&As[srow * 64 + scol + i * 8] = va[i];
      *(uint4*)&Bs[srow * 64 + scol + i * 8] = vb[i];
    }
    __syncthreads();
    if (k0 + 64 < K) {
      const ushort* na = ga + k0 + 64;
      const ushort* nb = gb + k0 + 64;
#pragma unroll
      for (int i = 0; i < 4; i++) { va[i] = ((const uint4*)na)[i]; vb[i] = ((const uint4*)nb)[i]; }
    }
#pragma unroll
    for (int kk = 0; kk < 2; kk++) {
      short8 af[4], bf[4];
#pragma unroll
      for (int mt = 0; mt < 4; mt++)
        af[mt] = *(const short8*)&As[(wm * 64 + mt * 16 + l16) * 64 + kk * 32 + q * 8];
#pragma unroll
      for (int nt = 0; nt < 4; nt++)
        bf[nt] = *(const short8*)&Bs[(wn * 64 + nt * 16 + l16) * 64 + kk * 32 + q * 8];
#pragma unroll
      for (int mt = 0; mt < 4; mt++)
#pragma unroll
        for (int nt = 0; nt < 4; nt++)
          acc[mt][nt] = __builtin_amdgcn_mfma_f32_16x16x32_bf16(af[mt], bf[nt], acc[mt][nt], 0, 0, 0);
    }
  }
  if (tmode == 0) {
#pragma unroll
    for (int mt = 0; mt < 4; mt++) {
#pragma unroll
      for (int nt = 0; nt < 4; nt++) {
        int col = bn * 128 + wn * 64 + nt * 16 + l16;
        float bv = bias[col];
#pragma unroll
        for (int r = 0; r < 4; r++) {
          int row = bm * 128 + wm * 64 + mt * 16 + q * 4 + r;
          float v = acc[mt][nt][r] + bv;
          if (relu) v = fmaxf(v, 0.f);
          C[(size_t)row * N + col] = f2bf(v);
        }
      }
    }
  } else {
#pragma unroll
    for (int mt = 0; mt < 4; mt++) {
#pragma unroll
      for (int nt = 0; nt < 4; nt++) {
        int col = bn * 128 + wn * 64 + nt * 16 + l16;
        float bv = bias[col];
        ushort4 pk;
        pk.x = f2bf(acc[mt][nt][0] + bv);
        pk.y = f2bf(acc[mt][nt][1] + bv);
        pk.z = f2bf(acc[mt][nt][2] + bv);
        pk.w = f2bf(acc[mt][nt][3] + bv);
        int row = bm * 128 + wm * 64 + mt * 16 + q * 4;
        *(ushort4*)&C[(size_t)col * CROWS + row] = pk;
      }
    }
  }
}

// ---------------- persistent BiLSTM recurrence chunk (one layer, both directions) ----------
// 32 blocks x 512 threads; processes global steps [s0, s0+CH).
// block = (d<<4)|part: d=dir, part owns h-cols [part*32, part*32+32).
// Sync: SELF-VALIDATING DATA. hout pre-filled with bf16-NaN sentinel (h is always finite,
// |h|<=1, never NaN). Consumers poll the h words themselves via agent-scope loads and accept
// each 8B word once all four bf16 halves != sentinel. No flags, no ordering hops.
__global__ __launch_bounds__(512, 1) void k_rec(const ushort* __restrict__ xgf,
                                                const ushort* __restrict__ xgb,
                                                const ushort* __restrict__ whr,
                                                ushort* __restrict__ hout,
                                                float* __restrict__ cstbuf,
                                                int s0) {
  __shared__ ushort hs[32 * 512];  // 32KB, rows XOR-swizzled by ((row&7)<<4) bytes
  const int tid = threadIdx.x, lane = tid & 63, w = tid >> 6;
  const int part = blockIdx.x & 15, d = blockIdx.x >> 4;
  const int l16 = lane & 15, q = lane >> 4;
  const ushort* xg = d ? xgb : xgf;   // transposed layout [2048][CROWS]
  float* cs = cstbuf + ((size_t)blockIdx.x * 512 + tid) * 8;

  short8 wf[16];
  {
    const ushort* p = whr + (((size_t)(d * 16 + part) * 8 + w) * 16 * 64 + lane) * 8;
#pragma unroll
    for (int kk = 0; kk < 16; kk++) wf[kk] = *(const short8*)(p + (size_t)kk * 64 * 8);
  }
  const int jj = w * 4 + (l16 >> 2), g = l16 & 3;
  const int gcol = g * 512 + part * 32 + jj;   // column in xg [2048], gate order i,f,g,o
  const int hcol = part * 32 + jj;             // column in h [512]
  float cst[2][4];
#pragma unroll
  for (int mt = 0; mt < 2; mt++)
#pragma unroll
    for (int r = 0; r < 4; r++) cst[mt][r] = (s0 == 0) ? 0.f : cs[mt * 4 + r];

  for (int ls = 0; ls < CH; ls++) {
    const int s = s0 + ls;
    const int pos = d ? (999 - s) : s;
    const int lp = d ? (CH - 1 - ls) : ls;    // local row block in xg chunk buffer
    // prefetch xt from transposed xg: 2x8B contiguous per thread (overlaps poll latency)
    const ushort* xc = xg + (size_t)gcol * CROWS + lp * 32 + q * 4;
    ushort4 xt0 = *(const ushort4*)(xc);        // rows q*4 + 0..3   (mt=0)
    ushort4 xt1 = *(const ushort4*)(xc + 16);   // rows 16+q*4+0..3  (mt=1)

    if (s == 0) {
      uint4 z4 = {0, 0, 0, 0};
#pragma unroll
      for (int i = 0; i < 4; i++) ((uint4*)hs)[tid * 4 + i] = z4;
    } else {
      const int prod = 2 * w + (lane >> 5);   // producer part gathered by this half-wave
      const int row = lane & 31;              // batch row
      const int ppos = d ? pos + 1 : pos - 1;
      const unsigned long long* gbase =
          (const unsigned long long*)(hout + ((size_t)ppos * 32 + row) * 1024 + d * 512 + prod * 32);
      unsigned long long hv8[8];
      unsigned pend = 0xFFu;   // poll-the-data: retry words still containing sentinel halves
      do {
#pragma unroll
        for (int k = 0; k < 8; k++)
          if (pend & (1u << k)) {
            hv8[k] = __hip_atomic_load(gbase + k, __ATOMIC_RELAXED, __HIP_MEMORY_SCOPE_AGENT);
            if (ok4(hv8[k])) pend &= ~(1u << k);
          }
      } while (__any(pend != 0));
      const int swz = (row & 7) << 4;
      char* L = (char*)hs + row * 1024;
      const int cb = prod * 64;
#pragma unroll
      for (int k = 0; k < 8; k++)
        *(unsigned long long*)(L + ((cb + k * 8) ^ swz)) = hv8[k];
    }
    __syncthreads();

    f32x4 za[2] = {};
#pragma unroll
    for (int kk = 0; kk < 16; kk++) {
#pragma unroll
      for (int mt = 0; mt < 2; mt++) {
        int row = mt * 16 + l16;
        int cb = kk * 64 + q * 16;
        short8 a = *(const short8*)((char*)hs + row * 1024 + (cb ^ ((row & 7) << 4)));
        za[mt] = __builtin_amdgcn_mfma_f32_16x16x32_bf16(a, wf[kk], za[mt], 0, 0, 0);
      }
    }

#pragma unroll
    for (int mt = 0; mt < 2; mt++) {
#pragma unroll
      for (int r = 0; r < 4; r++) {
        int bt = mt * 16 + q * 4 + r;
        ushort xr = (mt == 0) ? ((r == 0) ? xt0.x : (r == 1) ? xt0.y : (r == 2) ? xt0.z : xt0.w)
                              : ((r == 0) ? xt1.x : (r == 1) ? xt1.y : (r == 2) ? xt1.z : xt1.w);
        float z = za[mt][r] + bf2f(xr);
        int base = lane & ~3;
        float zi = __shfl(z, base + 0);
        float zf = __shfl(z, base + 1);
        float zg = __shfl(z, base + 2);
        float zo = __shfl(z, base + 3);
        float cn = sigm(zf) * cst[mt][r] + sigm(zi) * tanhft(zg);
        cst[mt][r] = cn;
        float hv = sigm(zo) * tanhft(cn);
        if (g == 0)
          __hip_atomic_store(hout + ((size_t)pos * 32 + bt) * 1024 + d * 512 + hcol, f2bf(hv),
                             __ATOMIC_RELAXED, __HIP_MEMORY_SCOPE_AGENT);
      }
    }
    __syncthreads();  // LDS lifecycle + vmcnt(0) drain keeps stores flowing every step
  }
#pragma unroll
  for (int mt = 0; mt < 2; mt++)
#pragma unroll
    for (int r = 0; r < 4; r++) cs[mt * 4 + r] = cst[mt][r];
}

// ---------------- dense: out[b][pos][29] = h2[row,1024] . W[1024,29] + bias ------------
__global__ __launch_bounds__(256, 2) void k_dense(const ushort* __restrict__ h2,
                                                  const float* __restrict__ wd,
                                                  const float* __restrict__ bd,
                                                  float* __restrict__ out) {
  __shared__ ushort rs[8 * 1024];
  const int tid = threadIdx.x;
  const int r0 = blockIdx.x * 8;
  const uint4* src = (const uint4*)(h2 + (size_t)r0 * 1024);
#pragma unroll
  for (int i = 0; i < 4; i++) ((uint4*)rs)[tid * 4 + i] = src[tid * 4 + i];
  __syncthreads();
  if (tid < 8 * V) {
    const int rr = tid / V, v = tid % V;
    float acc = bd[v];
    const ushort* rp = rs + rr * 1024;
#pragma unroll 8
    for (int k = 0; k < 1024; k++) acc += bf2f(rp[k]) * wd[(size_t)k * V + v];
    const int row = r0 + rr, pos = row >> 5, b = row & 31;
    out[((size_t)b * TT + pos) * V + v] = acc;
  }
}

// ---------------- host ----------------
extern "C" void kernel_launch(void* const* d_in, const int* in_sizes, int n_in,
                              void* d_out, int out_size, void* d_ws, size_t ws_size,
                              hipStream_t stream) {
  const float* x      = (const float*)d_in[0];
  const float* conv_w = (const float*)d_in[1];
  const float* conv_b = (const float*)d_in[2];
  const float* wi1f = (const float*)d_in[3];
  const float* wh1f = (const float*)d_in[4];
  const float* b1f  = (const float*)d_in[5];
  const float* wi1b = (const float*)d_in[6];
  const float* wh1b = (const float*)d_in[7];
  const float* b1b  = (const float*)d_in[8];
  const float* wi2f = (const float*)d_in[9];
  const float* wh2f = (const float*)d_in[10];
  const float* b2f  = (const float*)d_in[11];
  const float* wi2b = (const float*)d_in[12];
  const float* wh2b = (const float*)d_in[13];
  const float* b2b  = (const float*)d_in[14];
  const float* wd   = (const float*)d_in[15];
  const float* bd   = (const float*)d_in[16];
  float* out = (float*)d_out;

  char* ws = (char*)d_ws;
  size_t o = 0;
  auto alloc = [&](size_t sz) { size_t r = o; o = (o + sz + 255) & ~(size_t)255; return r; };
  const size_t oH2  = alloc((size_t)MROWS * 1024 * 2);  // 65.5MB; Y overlays first 16.4MB
  const size_t oY   = oH2;                              // conv out, dead before rec2 writes H2
  const size_t oXGF = alloc((size_t)CROWS * G4 * 2);    // 13.1MB chunk buffer (also im2col scratch)
  const size_t oXGB = alloc((size_t)CROWS * G4 * 2);
  const size_t oH1  = alloc((size_t)MROWS * 1024 * 2);
  const size_t oCW  = alloc((size_t)F * KC * 2);
  const size_t oW1F = alloc((size_t)G4 * F * 2);
  const size_t oW1B = alloc((size_t)G4 * F * 2);
  const size_t oW2F = alloc((size_t)G4 * 1024 * 2);
  const size_t oW2B = alloc((size_t)G4 * 1024 * 2);
  const size_t oR1  = alloc((size_t)(1 << 21) * 2);
  const size_t oR2  = alloc((size_t)(1 << 21) * 2);
  const size_t oCST = alloc((size_t)32 * 512 * 8 * 4);
  if (ws_size < o) return;  // workspace insufficient (~177MB needed)

  ushort* H2  = (ushort*)(ws + oH2);
  ushort* Y   = (ushort*)(ws + oY);
  ushort* XGF = (ushort*)(ws + oXGF);
  ushort* XGB = (ushort*)(ws + oXGB);
  ushort* H1  = (ushort*)(ws + oH1);
  ushort* CW  = (ushort*)(ws + oCW);
  ushort* W1F = (ushort*)(ws + oW1F);
  ushort* W1B = (ushort*)(ws + oW1B);
  ushort* W2F = (ushort*)(ws + oW2F);
  ushort* W2B = (ushort*)(ws + oW2B);
  ushort* R1  = (ushort*)(ws + oR1);
  ushort* R2  = (ushort*)(ws + oR2);
  float*  CST = (float*)(ws + oCST);

  const int N8 = MROWS * 1024 / 8;  // uint4 count for one h buffer
  hipLaunchKernelGGL(k_fillsent, dim3((N8 + 255) / 256), dim3(256), 0, stream, (uint4*)H1, N8);
  hipLaunchKernelGGL(k_convw, dim3((F * KC + 255) / 256), dim3(256), 0, stream, conv_w, CW);
  hipLaunchKernelGGL(k_transp, dim3((F * G4 + 255) / 256), dim3(256), 0, stream, wi1f, W1F, F, G4);
  hipLaunchKernelGGL(k_transp, dim3((F * G4 + 255) / 256), dim3(256), 0, stream, wi1b, W1B, F, G4);
  hipLaunchKernelGGL(k_transp, dim3((1024 * G4 + 255) / 256), dim3(256), 0, stream, wi2f, W2F, 1024, G4);
  hipLaunchKernelGGL(k_transp, dim3((1024 * G4 + 255) / 256), dim3(256), 0, stream, wi2b, W2B, 1024, G4);
  hipLaunchKernelGGL(k_whr, dim3((1 << 21) / 256), dim3(256), 0, stream, wh1f, wh1b, R1);
  hipLaunchKernelGGL(k_whr, dim3((1 << 21) / 256), dim3(256), 0, stream, wh2f, wh2b, R2);

  // conv as chunked im2col + GEMM (+bias+relu) -> Y bf16 [32000,256] (row-major)
  for (int p = 0; p < NCH; ++p) {
    hipLaunchKernelGGL(k_im2col, dim3((CROWS * KC + 255) / 256), dim3(256), 0, stream,
                       x, XGF, p * CH);
    hipLaunchKernelGGL(k_gemm, dim3(CROWS / 128, F / 128), dim3(256), 0, stream,
                       XGF, CW, conv_b, Y + (size_t)p * CROWS * F, F, KC, 1, 0);
  }
  // layer 1: chunked projections (transposed xg) + recurrence -> H1 [1000][32][1024]
  for (int p = 0; p < NCH; ++p) {
    hipLaunchKernelGGL(k_gemm, dim3(CROWS / 128, G4 / 128), dim3(256), 0, stream,
                       Y + (size_t)p * CROWS * F, W1F, b1f, XGF, G4, F, 0, 1);
    hipLaunchKernelGGL(k_gemm, dim3(CROWS / 128, G4 / 128), dim3(256), 0, stream,
                       Y + (size_t)(NCH - 1 - p) * CROWS * F, W1B, b1b, XGB, G4, F, 0, 1);
    hipLaunchKernelGGL(k_rec, dim3(32), dim3(512), 0, stream, XGF, XGB, R1, H1, CST, p * CH);
  }
  // sentinel-fill H2 now that Y (overlaid) is fully consumed, before layer-2 recurrence
  hipLaunchKernelGGL(k_fillsent, dim3((N8 + 255) / 256), dim3(256), 0, stream, (uint4*)H2, N8);
  // layer 2: chunked projections + recurrence -> H2
  for (int p = 0; p < NCH; ++p) {
    hipLaunchKernelGGL(k_gemm, dim3(CROWS / 128, G4 / 128), dim3(256), 0, stream,
                       H1 + (size_t)p * CROWS * 1024, W2F, b2f, XGF, G4, 1024, 0, 1);
    hipLaunchKernelGGL(k_gemm, dim3(CROWS / 128, G4 / 128), dim3(256), 0, stream,
                       H1 + (size_t)(NCH - 1 - p) * CROWS * 1024, W2B, b2b, XGB, G4, 1024, 0, 1);
    hipLaunchKernelGGL(k_rec, dim3(32), dim3(512), 0, stream, XGF, XGB, R2, H2, CST, p * CH);
  }
  // dense
  hipLaunchKernelGGL(k_dense, dim3(MROWS / 8), dim3(256), 0, stream, H2, wd, bd, out);
}

// Round 9
// 15804.492 us; speedup vs baseline: 1.0662x; 1.0587x over previous
//
#include <hip/hip_runtime.h>

// ---------------- constants ----------------
static constexpr int BB = 32, TI = 2000, TT = 1000, CIN = 80, F = 256, KW = 11;
static constexpr int G4 = 2048, V = 29;
static constexpr int MROWS = TT * BB;   // 32000
static constexpr int KC = 896;          // conv K (11*80=880) padded to mult of 64
static constexpr int CH = 100;          // steps per recurrence chunk
static constexpr int NCH = TT / CH;     // 10 chunks
static constexpr int CROWS = CH * BB;   // 3200 rows per chunk
static constexpr unsigned SENT = 0x7FC0u;            // bf16 NaN: h can never produce it
static constexpr unsigned SENT2 = 0x7FC07FC0u;

using short8 = __attribute__((ext_vector_type(8))) short;
using f32x4  = __attribute__((ext_vector_type(4))) float;
using u32x4  = __attribute__((ext_vector_type(4))) unsigned int;  // asm-friendly 128-bit

#define DEV __device__ __forceinline__

DEV ushort f2bf(float f) {
  unsigned u = __float_as_uint(f);
  unsigned r = (u + 0x7FFFu + ((u >> 16) & 1u)) >> 16;
  return (ushort)r;
}
DEV float bf2f(ushort h) { return __uint_as_float(((unsigned)h) << 16); }
DEV float sigm(float x) { return 1.f / (1.f + __expf(-x)); }
DEV float tanhft(float x) { return 1.f - 2.f / (__expf(2.f * x) + 1.f); }

// device-scope (MALL-coherent, sc1) wide ops for cross-block h exchange
DEV void ld64_sc1(const u32x4* p, u32x4* v) {
  asm volatile(
      "global_load_dwordx4 %0, %[a], off sc1\n\t"
      "global_load_dwordx4 %1, %[a], off offset:16 sc1\n\t"
      "global_load_dwordx4 %2, %[a], off offset:32 sc1\n\t"
      "global_load_dwordx4 %3, %[a], off offset:48 sc1\n\t"
      "s_waitcnt vmcnt(0)"
      : "=&v"(v[0]), "=&v"(v[1]), "=&v"(v[2]), "=&v"(v[3])
      : [a] "v"(p)
      : "memory");
}
DEV void st16_sc1(u32x4* p, u32x4 v) {
  asm volatile("global_store_dwordx4 %0, %1, off sc1" :: "v"(p), "v"(v) : "memory");
}

// any 16-bit half equals sentinel?
DEV int anysent(unsigned x) {
  unsigned y = x ^ SENT2;
  return ((y & 0xFFFFu) == 0u) | ((y >> 16) == 0u);
}
DEV int ok16(u32x4 v) {
  return !(anysent(v[0]) | anysent(v[1]) | anysent(v[2]) | anysent(v[3]));
}

// ---------------- prep kernels ----------------
// fill n8 * 8 ushorts with sentinel (uint4 = 8 bf16 per thread)
__global__ void k_fillsent(uint4* p, int n8) {
  int i = blockIdx.x * blockDim.x + threadIdx.x;
  if (i < n8) { uint4 s = {SENT2, SENT2, SENT2, SENT2}; p[i] = s; }
}

// conv_w [11][80][256] -> CW [256][896] bf16 (K padded w/ zeros)
__global__ void k_convw(const float* __restrict__ w, ushort* __restrict__ dst) {
  int idx = blockIdx.x * blockDim.x + threadIdx.x;
  if (idx >= F * KC) return;
  int f = idx / KC, kk = idx % KC;
  float v = (kk < KW * CIN) ? w[(size_t)kk * F + f] : 0.f;
  dst[idx] = f2bf(v);
}

// src [K][N] fp32 -> dst [N][K] bf16
__global__ void k_transp(const float* __restrict__ src, ushort* __restrict__ dst, int K, int N) {
  int idx = blockIdx.x * blockDim.x + threadIdx.x;
  if (idx >= K * N) return;
  int n = idx / K, k = idx % K;
  dst[idx] = f2bf(src[(size_t)k * N + n]);
}

// wh [512][2048] fp32 (f and b) -> packed MFMA B-fragments for the rec kernel.
// linear idx = ((((d*16+part)*8+w)*16+kk)*64+lane)*8 + j
__global__ void k_whr(const float* __restrict__ whf, const float* __restrict__ whb,
                      ushort* __restrict__ dst) {
  int idx = blockIdx.x * blockDim.x + threadIdx.x;
  if (idx >= (1 << 21)) return;
  int j = idx & 7, lane = (idx >> 3) & 63, kk = (idx >> 9) & 15;
  int w = (idx >> 13) & 7, part = (idx >> 16) & 15, d = (idx >> 20) & 1;
  int c16 = lane & 15, q = lane >> 4;
  int jj = w * 4 + (c16 >> 2), g = c16 & 3;
  int k = kk * 32 + q * 8 + j;
  int col = g * 512 + part * 32 + jj;
  const float* s = d ? whb : whf;
  dst[idx] = f2bf(s[(size_t)k * G4 + col]);
}

// x [32][2000][80] fp32 -> A0 [3200][896] bf16 im2col chunk (rows: (pos-pos0)*32+b)
__global__ void k_im2col(const float* __restrict__ x, ushort* __restrict__ A0, int pos0) {
  int idx = blockIdx.x * blockDim.x + threadIdx.x;
  if (idx >= CROWS * KC) return;
  int row = idx / KC, kk = idx % KC;
  int pos = pos0 + (row >> 5), b = row & 31;
  float v = 0.f;
  if (kk < KW * CIN) {
    int k = kk / CIN, c = kk % CIN;
    int tx = 2 * pos + k - 4;
    if (tx >= 0 && tx < TI) v = x[((size_t)b * TI + tx) * CIN + c];
  }
  A0[idx] = f2bf(v);
}

// ---------------- GEMM: C = A[.,K] * BT[N,K]^T + bias (bf16 in/out, fp32 acc) ----------
// grid (Mtiles, N/128). 128x128 tile, BK=64, 4 waves, 4x4 16x16 frags/wave.
// tmode=0: C[row*N+col] (optional relu). tmode=1: C[col*CROWS+row] packed 4-row stores.
__global__ __launch_bounds__(256, 2) void k_gemm(const ushort* __restrict__ A,
                                                 const ushort* __restrict__ BT,
                                                 const float* __restrict__ bias,
                                                 ushort* __restrict__ C,
                                                 int N, int K, int relu, int tmode) {
  __shared__ ushort As[128 * 64];
  __shared__ ushort Bs[128 * 64];
  const int tid = threadIdx.x;
  const int lane = tid & 63, wid = tid >> 6;
  const int wm = wid >> 1, wn = wid & 1;
  const int l16 = lane & 15, q = lane >> 4;
  const int bm = blockIdx.x, bn = blockIdx.y;
  const int srow = tid >> 1, scol = (tid & 1) * 32;
  const ushort* ga = A + (size_t)(bm * 128 + srow) * K + scol;
  const ushort* gb = BT + (size_t)(bn * 128 + srow) * K + scol;

  f32x4 acc[4][4] = {};
  uint4 va[4], vb[4];
#pragma unroll
  for (int i = 0; i < 4; i++) { va[i] = ((const uint4*)ga)[i]; vb[i] = ((const uint4*)gb)[i]; }

  for (int k0 = 0; k0 < K; k0 += 64) {
    __syncthreads();
#pragma unroll
    for (int i = 0; i < 4; i++) {
      *(uint4*)&As[srow * 64 + scol + i * 8] = va[i];
      *(uint4*)&Bs[srow * 64 + scol + i * 8] = vb[i];
    }
    __syncthreads();
    if (k0 + 64 < K) {
      const ushort* na = ga + k0 + 64;
      const ushort* nb = gb + k0 + 64;
#pragma unroll
      for (int i = 0; i < 4; i++) { va[i] = ((const uint4*)na)[i]; vb[i] = ((const uint4*)nb)[i]; }
    }
#pragma unroll
    for (int kk = 0; kk < 2; kk++) {
      short8 af[4], bf[4];
#pragma unroll
      for (int mt = 0; mt < 4; mt++)
        af[mt] = *(const short8*)&As[(wm * 64 + mt * 16 + l16) * 64 + kk * 32 + q * 8];
#pragma unroll
      for (int nt = 0; nt < 4; nt++)
        bf[nt] = *(const short8*)&Bs[(wn * 64 + nt * 16 + l16) * 64 + kk * 32 + q * 8];
#pragma unroll
      for (int mt = 0; mt < 4; mt++)
#pragma unroll
        for (int nt = 0; nt < 4; nt++)
          acc[mt][nt] = __builtin_amdgcn_mfma_f32_16x16x32_bf16(af[mt], bf[nt], acc[mt][nt], 0, 0, 0);
    }
  }
  if (tmode == 0) {
#pragma unroll
    for (int mt = 0; mt < 4; mt++) {
#pragma unroll
      for (int nt = 0; nt < 4; nt++) {
        int col = bn * 128 + wn * 64 + nt * 16 + l16;
        float bv = bias[col];
#pragma unroll
        for (int r = 0; r < 4; r++) {
          int row = bm * 128 + wm * 64 + mt * 16 + q * 4 + r;
          float v = acc[mt][nt][r] + bv;
          if (relu) v = fmaxf(v, 0.f);
          C[(size_t)row * N + col] = f2bf(v);
        }
      }
    }
  } else {
#pragma unroll
    for (int mt = 0; mt < 4; mt++) {
#pragma unroll
      for (int nt = 0; nt < 4; nt++) {
        int col = bn * 128 + wn * 64 + nt * 16 + l16;
        float bv = bias[col];
        ushort4 pk;
        pk.x = f2bf(acc[mt][nt][0] + bv);
        pk.y = f2bf(acc[mt][nt][1] + bv);
        pk.z = f2bf(acc[mt][nt][2] + bv);
        pk.w = f2bf(acc[mt][nt][3] + bv);
        int row = bm * 128 + wm * 64 + mt * 16 + q * 4;
        *(ushort4*)&C[(size_t)col * CROWS + row] = pk;
      }
    }
  }
}

// ---------------- persistent BiLSTM recurrence chunk (one layer, both directions) ----------
// 32 blocks x 512 threads; processes global steps [s0, s0+CH).
// block = (d<<4)|part: d=dir, part owns h-cols [part*32, part*32+32).
// Sync: self-validating data (bf16-NaN sentinel pre-fill). Producer stages its 2KB h-slice
// in LDS and emits it as 128x16B sc1 stores; consumers poll with batched 4x dwordx4 sc1
// loads (one vmcnt per round) until all halves are non-sentinel. No flags, no serial RTTs.
__global__ __launch_bounds__(512, 1) void k_rec(const ushort* __restrict__ xgf,
                                                const ushort* __restrict__ xgb,
                                                const ushort* __restrict__ whr,
                                                ushort* __restrict__ hout,
                                                float* __restrict__ cstbuf,
                                                int s0) {
  __shared__ ushort hs[32 * 512];   // 32KB, rows XOR-swizzled by ((row&7)<<4) bytes
  __shared__ ushort hstage[32 * 32];  // 2KB producer staging: [row][col-in-part]
  const int tid = threadIdx.x, lane = tid & 63, w = tid >> 6;
  const int part = blockIdx.x & 15, d = blockIdx.x >> 4;
  const int l16 = lane & 15, q = lane >> 4;
  const ushort* xg = d ? xgb : xgf;   // transposed layout [2048][CROWS]
  float* cs = cstbuf + ((size_t)blockIdx.x * 512 + tid) * 8;

  short8 wf[16];
  {
    const ushort* p = whr + (((size_t)(d * 16 + part) * 8 + w) * 16 * 64 + lane) * 8;
#pragma unroll
    for (int kk = 0; kk < 16; kk++) wf[kk] = *(const short8*)(p + (size_t)kk * 64 * 8);
  }
  const int jj = w * 4 + (l16 >> 2), g = l16 & 3;
  const int gcol = g * 512 + part * 32 + jj;   // column in xg [2048], gate order i,f,g,o
  float cst[2][4];
#pragma unroll
  for (int mt = 0; mt < 2; mt++)
#pragma unroll
    for (int r = 0; r < 4; r++) cst[mt][r] = (s0 == 0) ? 0.f : cs[mt * 4 + r];

  for (int ls = 0; ls < CH; ls++) {
    const int s = s0 + ls;
    const int pos = d ? (999 - s) : s;
    const int lp = d ? (CH - 1 - ls) : ls;    // local row block in xg chunk buffer
    // prefetch xt from transposed xg: 2x8B contiguous per thread (overlaps poll latency)
    const ushort* xc = xg + (size_t)gcol * CROWS + lp * 32 + q * 4;
    ushort4 xt0 = *(const ushort4*)(xc);        // rows q*4 + 0..3   (mt=0)
    ushort4 xt1 = *(const ushort4*)(xc + 16);   // rows 16+q*4+0..3  (mt=1)

    if (s == 0) {
      uint4 z4 = {0, 0, 0, 0};
#pragma unroll
      for (int i = 0; i < 4; i++) ((uint4*)hs)[tid * 4 + i] = z4;
    } else {
      const int prod = 2 * w + (lane >> 5);   // producer part gathered by this half-wave
      const int row = lane & 31;              // batch row
      const int ppos = d ? pos + 1 : pos - 1;
      const u32x4* gb =
          (const u32x4*)(hout + ((size_t)ppos * 32 + row) * 1024 + d * 512 + prod * 32);
      u32x4 v[4];
      // batched poll-the-data: 4x16B per round, single vmcnt; sentinel halves flip once
      do {
        ld64_sc1(gb, v);
      } while (__any(!(ok16(v[0]) & ok16(v[1]) & ok16(v[2]) & ok16(v[3]))));
      const int swz = (row & 7) << 4;
      char* L = (char*)hs + row * 1024;
      const int cb = prod * 64;
#pragma unroll
      for (int k = 0; k < 4; k++)
        *(u32x4*)(L + ((cb + k * 16) ^ swz)) = v[k];
    }
    __syncthreads();

    f32x4 za[2] = {};
#pragma unroll
    for (int kk = 0; kk < 16; kk++) {
#pragma unroll
      for (int mt = 0; mt < 2; mt++) {
        int row = mt * 16 + l16;
        int cb = kk * 64 + q * 16;
        short8 a = *(const short8*)((char*)hs + row * 1024 + (cb ^ ((row & 7) << 4)));
        za[mt] = __builtin_amdgcn_mfma_f32_16x16x32_bf16(a, wf[kk], za[mt], 0, 0, 0);
      }
    }

#pragma unroll
    for (int mt = 0; mt < 2; mt++) {
#pragma unroll
      for (int r = 0; r < 4; r++) {
        int bt = mt * 16 + q * 4 + r;
        ushort xr = (mt == 0) ? ((r == 0) ? xt0.x : (r == 1) ? xt0.y : (r == 2) ? xt0.z : xt0.w)
                              : ((r == 0) ? xt1.x : (r == 1) ? xt1.y : (r == 2) ? xt1.z : xt1.w);
        float z = za[mt][r] + bf2f(xr);
        int base = lane & ~3;
        float zi = __shfl(z, base + 0);
        float zf = __shfl(z, base + 1);
        float zg = __shfl(z, base + 2);
        float zo = __shfl(z, base + 3);
        float cn = sigm(zf) * cst[mt][r] + sigm(zi) * tanhft(zg);
        cst[mt][r] = cn;
        float hv = sigm(zo) * tanhft(cn);
        if (g == 0) hstage[bt * 32 + jj] = f2bf(hv);   // stage to LDS (coalesced store later)
      }
    }
    __syncthreads();  // hstage complete; hs free for next iteration
    // coalesced producer store: wave w emits rows 4w..4w+3 as 16B sc1 stores (fire & forget)
    if ((lane & 12) == 0) {
      const int rr = 4 * w + (lane >> 4);
      const int ck = lane & 3;
      u32x4 dv = *(u32x4*)((char*)hstage + rr * 64 + ck * 16);
      st16_sc1((u32x4*)(hout + ((size_t)pos * 32 + rr) * 1024 + d * 512 + part * 32) + ck, dv);
    }
  }
#pragma unroll
  for (int mt = 0; mt < 2; mt++)
#pragma unroll
    for (int r = 0; r < 4; r++) cs[mt * 4 + r] = cst[mt][r];
}

// ---------------- dense: out[b][pos][29] = h2[row,1024] . W[1024,29] + bias ------------
__global__ __launch_bounds__(256, 2) void k_dense(const ushort* __restrict__ h2,
                                                  const float* __restrict__ wd,
                                                  const float* __restrict__ bd,
                                                  float* __restrict__ out) {
  __shared__ ushort rs[8 * 1024];
  const int tid = threadIdx.x;
  const int r0 = blockIdx.x * 8;
  const uint4* src = (const uint4*)(h2 + (size_t)r0 * 1024);
#pragma unroll
  for (int i = 0; i < 4; i++) ((uint4*)rs)[tid * 4 + i] = src[tid * 4 + i];
  __syncthreads();
  if (tid < 8 * V) {
    const int rr = tid / V, v = tid % V;
    float acc = bd[v];
    const ushort* rp = rs + rr * 1024;
#pragma unroll 8
    for (int k = 0; k < 1024; k++) acc += bf2f(rp[k]) * wd[(size_t)k * V + v];
    const int row = r0 + rr, pos = row >> 5, b = row & 31;
    out[((size_t)b * TT + pos) * V + v] = acc;
  }
}

// ---------------- host ----------------
extern "C" void kernel_launch(void* const* d_in, const int* in_sizes, int n_in,
                              void* d_out, int out_size, void* d_ws, size_t ws_size,
                              hipStream_t stream) {
  const float* x      = (const float*)d_in[0];
  const float* conv_w = (const float*)d_in[1];
  const float* conv_b = (const float*)d_in[2];
  const float* wi1f = (const float*)d_in[3];
  const float* wh1f = (const float*)d_in[4];
  const float* b1f  = (const float*)d_in[5];
  const float* wi1b = (const float*)d_in[6];
  const float* wh1b = (const float*)d_in[7];
  const float* b1b  = (const float*)d_in[8];
  const float* wi2f = (const float*)d_in[9];
  const float* wh2f = (const float*)d_in[10];
  const float* b2f  = (const float*)d_in[11];
  const float* wi2b = (const float*)d_in[12];
  const float* wh2b = (const float*)d_in[13];
  const float* b2b  = (const float*)d_in[14];
  const float* wd   = (const float*)d_in[15];
  const float* bd   = (const float*)d_in[16];
  float* out = (float*)d_out;

  char* ws = (char*)d_ws;
  size_t o = 0;
  auto alloc = [&](size_t sz) { size_t r = o; o = (o + sz + 255) & ~(size_t)255; return r; };
  const size_t oH2  = alloc((size_t)MROWS * 1024 * 2);  // 65.5MB; Y overlays first 16.4MB
  const size_t oY   = oH2;                              // conv out, dead before rec2 writes H2
  const size_t oXGF = alloc((size_t)CROWS * G4 * 2);    // 13.1MB chunk buffer (also im2col scratch)
  const size_t oXGB = alloc((size_t)CROWS * G4 * 2);
  const size_t oH1  = alloc((size_t)MROWS * 1024 * 2);
  const size_t oCW  = alloc((size_t)F * KC * 2);
  const size_t oW1F = alloc((size_t)G4 * F * 2);
  const size_t oW1B = alloc((size_t)G4 * F * 2);
  const size_t oW2F = alloc((size_t)G4 * 1024 * 2);
  const size_t oW2B = alloc((size_t)G4 * 1024 * 2);
  const size_t oR1  = alloc((size_t)(1 << 21) * 2);
  const size_t oR2  = alloc((size_t)(1 << 21) * 2);
  const size_t oCST = alloc((size_t)32 * 512 * 8 * 4);
  if (ws_size < o) return;  // workspace insufficient (~177MB needed)

  ushort* H2  = (ushort*)(ws + oH2);
  ushort* Y   = (ushort*)(ws + oY);
  ushort* XGF = (ushort*)(ws + oXGF);
  ushort* XGB = (ushort*)(ws + oXGB);
  ushort* H1  = (ushort*)(ws + oH1);
  ushort* CW  = (ushort*)(ws + oCW);
  ushort* W1F = (ushort*)(ws + oW1F);
  ushort* W1B = (ushort*)(ws + oW1B);
  ushort* W2F = (ushort*)(ws + oW2F);
  ushort* W2B = (ushort*)(ws + oW2B);
  ushort* R1  = (ushort*)(ws + oR1);
  ushort* R2  = (ushort*)(ws + oR2);
  float*  CST = (float*)(ws + oCST);

  const int N8 = MROWS * 1024 / 8;  // uint4 count for one h buffer
  hipLaunchKernelGGL(k_fillsent, dim3((N8 + 255) / 256), dim3(256), 0, stream, (uint4*)H1, N8);
  hipLaunchKernelGGL(k_convw, dim3((F * KC + 255) / 256), dim3(256), 0, stream, conv_w, CW);
  hipLaunchKernelGGL(k_transp, dim3((F * G4 + 255) / 256), dim3(256), 0, stream, wi1f, W1F, F, G4);
  hipLaunchKernelGGL(k_transp, dim3((F * G4 + 255) / 256), dim3(256), 0, stream, wi1b, W1B, F, G4);
  hipLaunchKernelGGL(k_transp, dim3((1024 * G4 + 255) / 256), dim3(256), 0, stream, wi2f, W2F, 1024, G4);
  hipLaunchKernelGGL(k_transp, dim3((1024 * G4 + 255) / 256), dim3(256), 0, stream, wi2b, W2B, 1024, G4);
  hipLaunchKernelGGL(k_whr, dim3((1 << 21) / 256), dim3(256), 0, stream, wh1f, wh1b, R1);
  hipLaunchKernelGGL(k_whr, dim3((1 << 21) / 256), dim3(256), 0, stream, wh2f, wh2b, R2);

  // conv as chunked im2col + GEMM (+bias+relu) -> Y bf16 [32000,256] (row-major)
  for (int p = 0; p < NCH; ++p) {
    hipLaunchKernelGGL(k_im2col, dim3((CROWS * KC + 255) / 256), dim3(256), 0, stream,
                       x, XGF, p * CH);
    hipLaunchKernelGGL(k_gemm, dim3(CROWS / 128, F / 128), dim3(256), 0, stream,
                       XGF, CW, conv_b, Y + (size_t)p * CROWS * F, F, KC, 1, 0);
  }
  // layer 1: chunked projections (transposed xg) + recurrence -> H1 [1000][32][1024]
  for (int p = 0; p < NCH; ++p) {
    hipLaunchKernelGGL(k_gemm, dim3(CROWS / 128, G4 / 128), dim3(256), 0, stream,
                       Y + (size_t)p * CROWS * F, W1F, b1f, XGF, G4, F, 0, 1);
    hipLaunchKernelGGL(k_gemm, dim3(CROWS / 128, G4 / 128), dim3(256), 0, stream,
                       Y + (size_t)(NCH - 1 - p) * CROWS * F, W1B, b1b, XGB, G4, F, 0, 1);
    hipLaunchKernelGGL(k_rec, dim3(32), dim3(512), 0, stream, XGF, XGB, R1, H1, CST, p * CH);
  }
  // sentinel-fill H2 now that Y (overlaid) is fully consumed, before layer-2 recurrence
  hipLaunchKernelGGL(k_fillsent, dim3((N8 + 255) / 256), dim3(256), 0, stream, (uint4*)H2, N8);
  // layer 2: chunked projections + recurrence -> H2
  for (int p = 0; p < NCH; ++p) {
    hipLaunchKernelGGL(k_gemm, dim3(CROWS / 128, G4 / 128), dim3(256), 0, stream,
                       H1 + (size_t)p * CROWS * 1024, W2F, b2f, XGF, G4, 1024, 0, 1);
    hipLaunchKernelGGL(k_gemm, dim3(CROWS / 128, G4 / 128), dim3(256), 0, stream,
                       H1 + (size_t)(NCH - 1 - p) * CROWS * 1024, W2B, b2b, XGB, G4, 1024, 0, 1);
    hipLaunchKernelGGL(k_rec, dim3(32), dim3(512), 0, stream, XGF, XGB, R2, H2, CST, p * CH);
  }
  // dense
  hipLaunchKernelGGL(k_dense, dim3(MROWS / 8), dim3(256), 0, stream, H2, wd, bd, out);
}